// Round 5
// baseline (604.315 us; speedup 1.0000x reference)
//
#include <hip/hip_runtime.h>

// VQ-VAE codebook lookup: z_e [32,2048,64] f32, codebook [1024,64] f32.
// Out = concat(z_q [65536*64] f32, indices [65536] written as f32).
// argmin_k ||x - c_k||^2 == argmin_k (c2[k] - 2*x.c_k)  (x2 row-constant).
//
// Broadcast-stream design (no LDS in hot loop): each wave scans a 256-code
// quarter for its 64 rows (lane = row). Codebook addresses are wave-uniform
// -> one 64B request per float4 (or SMEM s_load if LLVM scalarizes). x row
// lives in 16 float4 VGPRs. Inner loop = pure register FMA, no barriers,
// no lgkmcnt chains. 4-wave lexicographic (dist, idx) merge in LDS at end.

#define N_ROWS  65536
#define D       64
#define K_CODES 1024
#define QUARTER 256

__global__ __launch_bounds__(256) void c2_kernel(const float* __restrict__ cb,
                                                 float* __restrict__ c2) {
    int c = blockIdx.x * 256 + threadIdx.x;
    if (c >= K_CODES) return;
    const float4* row = (const float4*)(cb + c * D);
    float s0 = 0.f, s1 = 0.f, s2 = 0.f, s3 = 0.f;
#pragma unroll
    for (int i = 0; i < D / 4; ++i) {
        float4 v = row[i];
        s0 = fmaf(v.x, v.x, s0);
        s1 = fmaf(v.y, v.y, s1);
        s2 = fmaf(v.z, v.z, s2);
        s3 = fmaf(v.w, v.w, s3);
    }
    c2[c] = (s0 + s1) + (s2 + s3);
}

// 16 FMAs of one 4-float4 group into 8 accumulators.
#define G_FMA(P0, P1, P2, P3, XA, XB, XC, XD)                                  \
    a0 = fmaf(P0.x, XA.x, a0); a1 = fmaf(P0.y, XA.y, a1);                      \
    a2 = fmaf(P0.z, XA.z, a2); a3 = fmaf(P0.w, XA.w, a3);                      \
    a4 = fmaf(P1.x, XB.x, a4); a5 = fmaf(P1.y, XB.y, a5);                      \
    a6 = fmaf(P1.z, XB.z, a6); a7 = fmaf(P1.w, XB.w, a7);                      \
    a0 = fmaf(P2.x, XC.x, a0); a1 = fmaf(P2.y, XC.y, a1);                      \
    a2 = fmaf(P2.z, XC.z, a2); a3 = fmaf(P2.w, XC.w, a3);                      \
    a4 = fmaf(P3.x, XD.x, a4); a5 = fmaf(P3.y, XD.y, a5);                      \
    a6 = fmaf(P3.z, XD.z, a6); a7 = fmaf(P3.w, XD.w, a7)

// Same but initializes the accumulators (saves 8 movs per code).
#define G_MUL(P0, P1, P2, P3, XA, XB, XC, XD)                                  \
    a0 = P0.x * XA.x; a1 = P0.y * XA.y; a2 = P0.z * XA.z; a3 = P0.w * XA.w;    \
    a4 = P1.x * XB.x; a5 = P1.y * XB.y; a6 = P1.z * XB.z; a7 = P1.w * XB.w;    \
    a0 = fmaf(P2.x, XC.x, a0); a1 = fmaf(P2.y, XC.y, a1);                      \
    a2 = fmaf(P2.z, XC.z, a2); a3 = fmaf(P2.w, XC.w, a3);                      \
    a4 = fmaf(P3.x, XD.x, a4); a5 = fmaf(P3.y, XD.y, a5);                      \
    a6 = fmaf(P3.z, XD.z, a6); a7 = fmaf(P3.w, XD.w, a7)

__global__ __launch_bounds__(256, 3) void vq_kernel(const float* __restrict__ z_e,
                                                    const float* __restrict__ cb,
                                                    const float* __restrict__ c2g,
                                                    float* __restrict__ out) {
    __shared__ float s_best[4][64];
    __shared__ int   s_bidx[4][64];
    __shared__ int   s_win[64];

    const int tid  = threadIdx.x;
    const int w    = tid >> 6;          // wave 0..3 -> code quarter
    const int lane = tid & 63;          // lane -> row within block
    const int row  = blockIdx.x * 64 + lane;

    // x row in registers: 16 float4 (static indices only).
    const float4* xr = (const float4*)(z_e + (size_t)row * D);
    float4 x[16];
#pragma unroll
    for (int i = 0; i < 16; ++i) x[i] = xr[i];

    const int    k0    = w * QUARTER;
    const float* cbase = cb + (size_t)k0 * D;

    float best = 3.4e38f;
    int   bidx = k0;

    // Rotating p/q float4-groups: each load group is issued 2 FMA-groups
    // (32 FMA = 64 cyc) before use; 3 waves/SIMD TLP covers the rest.
    float4 p0, p1, p2, p3, q0, q1, q2, q3;
    {
        const float4* c0p = (const float4*)cbase;
        p0 = c0p[0]; p1 = c0p[1]; p2 = c0p[2]; p3 = c0p[3];
    }

#pragma unroll 2
    for (int k = 0; k < QUARTER; ++k) {
        const float4* cp = (const float4*)(cbase + (size_t)k * D);
        const float4* cn = (const float4*)(cbase +
                             (size_t)(k + 1 < QUARTER ? k + 1 : k) * D);
        const float c2k = c2g[k0 + k];          // wave-uniform
        float a0, a1, a2, a3, a4, a5, a6, a7;

        q0 = cp[4];  q1 = cp[5];  q2 = cp[6];  q3 = cp[7];
        G_MUL(p0, p1, p2, p3, x[0], x[1], x[2], x[3]);      // chunks 0..3
        p0 = cp[8];  p1 = cp[9];  p2 = cp[10]; p3 = cp[11];
        G_FMA(q0, q1, q2, q3, x[4], x[5], x[6], x[7]);      // chunks 4..7
        q0 = cp[12]; q1 = cp[13]; q2 = cp[14]; q3 = cp[15];
        G_FMA(p0, p1, p2, p3, x[8], x[9], x[10], x[11]);    // chunks 8..11
        p0 = cn[0];  p1 = cn[1];  p2 = cn[2];  p3 = cn[3];  // next code 0..3
        G_FMA(q0, q1, q2, q3, x[12], x[13], x[14], x[15]);  // chunks 12..15

        const float dot  = ((a0 + a1) + (a2 + a3)) + ((a4 + a5) + (a6 + a7));
        const float dist = fmaf(-2.f, dot, c2k);
        if (dist < best) { best = dist; bidx = k0 + k; }    // strict <: earliest
    }

    // ---- merge across the 4 quarters (lexicographic (dist, idx)) ----
    s_best[w][lane] = best;
    s_bidx[w][lane] = bidx;
    __syncthreads();

    if (tid < 64) {
        float b  = s_best[0][lane];
        int   bi = s_bidx[0][lane];
#pragma unroll
        for (int w2 = 1; w2 < 4; ++w2) {
            const float ob = s_best[w2][lane];
            const int   oi = s_bidx[w2][lane];
            if (ob < b || (ob == b && oi < bi)) { b = ob; bi = oi; }
        }
        s_win[lane] = bi;
        out[(size_t)N_ROWS * D + row] = (float)bi;   // coalesced index write
    }
    __syncthreads();

    // ---- z_q write: thread (w, lane) writes 16 floats of row `lane` ----
    {
        const int bi = s_win[lane];
        const float4* src = (const float4*)(cb + (size_t)bi * D) + w * 4;
        float4*       dst = (float4*)(out + (size_t)row * D) + w * 4;
#pragma unroll
        for (int i = 0; i < 4; ++i) dst[i] = src[i];
    }
}

extern "C" void kernel_launch(void* const* d_in, const int* in_sizes, int n_in,
                              void* d_out, int out_size, void* d_ws, size_t ws_size,
                              hipStream_t stream) {
    const float* z_e = (const float*)d_in[0];
    const float* cb  = (const float*)d_in[1];
    float* out = (float*)d_out;
    float* c2  = (float*)d_ws;  // 1024 floats scratch

    hipLaunchKernelGGL(c2_kernel, dim3(K_CODES / 256), dim3(256), 0, stream, cb, c2);
    hipLaunchKernelGGL(vq_kernel, dim3(N_ROWS / 64), dim3(256), 0, stream,
                       z_e, cb, c2, out);
}